// Round 3
// baseline (171.056 us; speedup 1.0000x reference)
//
#include <hip/hip_runtime.h>
#include <hip/hip_bf16.h>
#include <type_traits>

// Windowed attention smoothing via MFMA — barrier-free, per-wave autonomous.
// v4: bf16 LDS band (staging converts fp32->bf16 once; fragments are direct
// ds_read_b128 — no per-tile cvt chain). P4's fp32 window (aw) reads global,
// issued at tile top (rows are L1/L2-hot from last iteration's staging);
// sched_barrier(0) pins the loads early (v2 lesson: compiler sinks them).
// LDS 9216 B/wave -> 36864/block -> 4 blocks/CU -> 16 waves/CU (occ 50%).
// No __syncthreads: LDS regions are wave-private; DS pipe is in-order
// within a wave.
//
// rows=200000, RANK=64, WINDOW=11. Block=256 (4 waves), 16 rows/wave/tile,
// persistent grid-stride loop over 64-row block-tiles, grid=1024.

constexpr int RANK   = 64;
constexpr int WINDOW = 11;
constexpr int PAD    = 5;
constexpr int TILE   = 16;   // rows per wave
constexpr int BLOCK  = 256;  // 4 waves
constexpr int TR     = 64;   // rows per block-tile
constexpr int BSH    = 72;   // bf16 row stride (144 B): 16B-aligned, rows
                             // advance 36 banks -> b128 reads/writes balanced
constexpr int SC_S   = 18;   // f32 elems per Sc row (breaks pow2)
constexpr int GRIDB  = 1024; // 4 resident blocks/CU x 256 CU

typedef short short8  __attribute__((ext_vector_type(8)));
typedef float float4v __attribute__((ext_vector_type(4)));

__device__ __forceinline__ short8 cvt_bf8(float4 a, float4 b) {
    union { short8 s; __hip_bfloat162 h[4]; } u;
    u.h[0] = __float22bfloat162_rn(make_float2(a.x, a.y));
    u.h[1] = __float22bfloat162_rn(make_float2(a.z, a.w));
    u.h[2] = __float22bfloat162_rn(make_float2(b.x, b.y));
    u.h[3] = __float22bfloat162_rn(make_float2(b.z, b.w));
    return u.s;
}

__device__ __forceinline__ float fast_tanh(float x) {
    return 1.0f - 2.0f / (1.0f + __expf(2.0f * x));
}

__global__ __launch_bounds__(BLOCK, 4) void attn_win_kernel(
    const float* __restrict__ A,   // (rows, 64)
    const float* __restrict__ W,   // (64, 64) row-major (out,in)
    const float* __restrict__ b,   // (64,)
    float* __restrict__ out,       // (rows, 64)
    int rows)
{
    // Per-wave LDS: band 4608 + V1 2304 + Sc 2304 = 9216 B; x4 = 36864 B
    __shared__ __align__(16) __hip_bfloat16 band[4][32][BSH];
    __shared__ __align__(16) __hip_bfloat16 V1[4][TILE][BSH];
    __shared__ __align__(16) float          Sc[4][32][SC_S];

    const int lane = threadIdx.x & 63;
    const int wv   = threadIdx.x >> 6;
    const int m16  = lane & 15;
    const int quad = lane >> 4;
    const int srow = lane >> 3;       // staging: row within group-of-8
    const int scb  = (lane & 7) * 8;  // staging: col base (8 elems, 32B fp32)

    // ---- Persistent W fragments (32 VGPRs) + bias, converted ONCE per wave ----
    short8 wfrag[4][2];  // [ct][kf]: W[n=ct*16+m16][kf*32 + quad*8 + j]
    #pragma unroll
    for (int ct = 0; ct < 4; ct++) {
        #pragma unroll
        for (int kf = 0; kf < 2; kf++) {
            const float4* p =
                (const float4*)(W + (ct * 16 + m16) * RANK + kf * 32 + quad * 8);
            wfrag[ct][kf] = cvt_bf8(p[0], p[1]);
        }
    }
    float bias[4];
    #pragma unroll
    for (int ct = 0; ct < 4; ct++) bias[ct] = b[ct * 16 + m16];

    const int n_btiles = (rows + TR - 1) / TR;
    int bt = blockIdx.x;
    if (bt >= n_btiles) return;

    // ---- prologue: stage FIRST tile's 32-row band as bf16 ----
    // (OOB rows -> zeros, matching jnp.pad semantics; covers bt=0 and tail)
    {
        const int rw0 = bt * TR + wv * TILE;
        #pragma unroll
        for (int ro = 0; ro < 4; ro++) {
            const int g = rw0 - PAD + ro * 8 + srow;
            float4 x0 = make_float4(0.f, 0.f, 0.f, 0.f), x1 = x0;
            if ((unsigned)g < (unsigned)rows) {
                const float4* p = (const float4*)(A + (size_t)g * RANK + scb);
                x0 = p[0]; x1 = p[1];
            }
            *(short8*)&band[wv][ro * 8 + srow][scb] = cvt_bf8(x0, x1);
        }
    }

    for (; bt < n_btiles; bt += gridDim.x) {
        const int rw = bt * TR + wv * TILE;   // this wave's rows rw..rw+15

        auto body = [&](auto GC) {
            constexpr bool G = decltype(GC)::value;

            // ---- M1 A-frags: direct bf16 ds_read_b128 (no cvt) ----
            short8 am1[2];   // rows rw+m16 = band row PAD+m16
            #pragma unroll
            for (int kf = 0; kf < 2; kf++)
                am1[kf] =
                    *(const short8*)&band[wv][PAD + m16][kf * 32 + quad * 8];

            // ---- aw: fp32 window from GLOBAL, issued at tile top.
            //      These rows were staged (fetched) last iteration by this
            //      wave -> L1/L2-hot; latency hides under M1+M2+softmax. ----
            float aw[26];
            #pragma unroll
            for (int s = 0; s < 26; s++) {
                const int gr = rw - PAD + s;
                if (!G || (unsigned)gr < (unsigned)rows)
                    aw[s] = A[(size_t)gr * RANK + lane];
                else
                    aw[s] = 0.0f;
            }

            // ---- NEXT tile's stage loads (fp32), issued EARLY; cvt+LDS-write
            //      deferred to after softmax (HBM-cold rows, ~900cy to hide) ----
            float4 sx[8];
            {
                const int rwn = rw + (int)gridDim.x * TR;
                #pragma unroll
                for (int ro = 0; ro < 4; ro++) {
                    const int g = rwn - PAD + ro * 8 + srow;
                    if ((unsigned)g < (unsigned)rows) {
                        const float4* p =
                            (const float4*)(A + (size_t)g * RANK + scb);
                        sx[2 * ro]     = p[0];
                        sx[2 * ro + 1] = p[1];
                    } else {
                        sx[2 * ro] = make_float4(0.f, 0.f, 0.f, 0.f);
                        sx[2 * ro + 1] = sx[2 * ro];
                    }
                }
            }
            // Pin all loads above this point (v2 lesson: without this the
            // scheduler sinks them to their uses and the latency is exposed).
            __builtin_amdgcn_sched_barrier(0);

            // ---- M1: V1 = tanh(A[rw..rw+15] @ W^T + b) ----
            float4v acc[4];
            #pragma unroll
            for (int ct = 0; ct < 4; ct++)
                acc[ct] = (float4v){bias[ct], bias[ct], bias[ct], bias[ct]};
            #pragma unroll
            for (int kf = 0; kf < 2; kf++)
                #pragma unroll
                for (int ct = 0; ct < 4; ct++)
                    acc[ct] = __builtin_amdgcn_mfma_f32_16x16x32_bf16(
                        am1[kf], wfrag[ct][kf], acc[ct], 0, 0, 0);
            // epilogue: element (row q=quad*4+rg, col c=ct*16+m16) -> V1[q][c]
            #pragma unroll
            for (int ct = 0; ct < 4; ct++)
                #pragma unroll
                for (int rg = 0; rg < 4; rg++)
                    V1[wv][quad * 4 + rg][ct * 16 + m16] =
                        __float2bfloat16(fast_tanh(acc[ct][rg]));

            // ---- abnd frags read AFTER M1 (cuts peak register pressure) ----
            short8 abnd[2][2];  // band rows i=it*16+m16
            #pragma unroll
            for (int it = 0; it < 2; it++)
                #pragma unroll
                for (int kf = 0; kf < 2; kf++)
                    abnd[it][kf] = *(const short8*)
                        &band[wv][it * 16 + m16][kf * 32 + quad * 8];

            // ---- M2: S[i][q] = dot(band[i], v1[q]) ----
            float4v sacc[2];
            sacc[0] = (float4v){0.f, 0.f, 0.f, 0.f};
            sacc[1] = (float4v){0.f, 0.f, 0.f, 0.f};
            #pragma unroll
            for (int kf = 0; kf < 2; kf++) {
                const short8 bfr =
                    *(const short8*)&V1[wv][m16][kf * 32 + quad * 8];
                #pragma unroll
                for (int it = 0; it < 2; it++)
                    sacc[it] = __builtin_amdgcn_mfma_f32_16x16x32_bf16(
                        abnd[it][kf], bfr, sacc[it], 0, 0, 0);
            }
            // scatter S (i = it*16+quad*4+rg, q = m16); rows 26..31 are dead
            #pragma unroll
            for (int it = 0; it < 2; it++)
                #pragma unroll
                for (int rg = 0; rg < 4; rg++)
                    Sc[wv][it * 16 + quad * 4 + rg][m16] = sacc[it][rg];

            // ---- softmax over band i in [q, q+10] of column q=m16 ----
            // (redundant across quads; lane rr<16 holds row rw+rr's probs)
            float p[WINDOW];
            {
                float s[WINDOW];
                float mx = -1e30f;
                #pragma unroll
                for (int w = 0; w < WINDOW; w++) {
                    s[w] = Sc[wv][m16 + w][m16];
                    mx = fmaxf(mx, s[w]);
                }
                float den = 0.0f;
                #pragma unroll
                for (int w = 0; w < WINDOW; w++) {
                    p[w] = __expf((s[w] - mx) * 0.125f);  // 1/sqrt(64) folded
                    den += p[w];
                }
                const float rden = __fdividef(1.0f, den);
                #pragma unroll
                for (int w = 0; w < WINDOW; w++) p[w] *= rden;
            }

            // ---- overwrite band with NEXT tile (cvt now; loads landed).
            //      Safe: current band's last reads (abnd) issued above;
            //      DS pipe is in-order within a wave. ----
            #pragma unroll
            for (int ro = 0; ro < 4; ro++)
                *(short8*)&band[wv][ro * 8 + srow][scb] =
                    cvt_bf8(sx[2 * ro], sx[2 * ro + 1]);

            // ---- P4: out[rw+rr][lane] = sum_w p[rr][w] * aw[rr+w] ----
            #pragma unroll
            for (int rr = 0; rr < TILE; rr++) {
                float o = 0.0f;
                #pragma unroll
                for (int w = 0; w < WINDOW; w++) {
                    const float pw = __uint_as_float(
                        __builtin_amdgcn_readlane(__float_as_uint(p[w]), rr));
                    o = fmaf(pw, aw[rr + w], o);
                }
                if (!G || rw + rr < rows)
                    out[(size_t)(rw + rr) * RANK + lane] = o;
            }
        };

        // Interior iff no guarded row can be <0 (bt>0) or >=rows
        // (conservative: max touched row < bt*TR + 89).
        const bool interior = (bt > 0) && (bt * TR + 89 <= rows);
        if (interior)
            body(std::integral_constant<bool, false>{});
        else
            body(std::integral_constant<bool, true>{});
    }
}

extern "C" void kernel_launch(void* const* d_in, const int* in_sizes, int n_in,
                              void* d_out, int out_size, void* d_ws, size_t ws_size,
                              hipStream_t stream) {
    const float* A = (const float*)d_in[0];
    const float* W = (const float*)d_in[1];
    const float* b = (const float*)d_in[2];
    float* out = (float*)d_out;

    const int rows     = in_sizes[0] / RANK;
    const int n_btiles = (rows + TR - 1) / TR;
    const int blocks   = n_btiles < GRIDB ? n_btiles : GRIDB;  // persistent

    hipLaunchKernelGGL(attn_win_kernel, dim3(blocks), dim3(BLOCK), 0, stream,
                       A, W, b, out, rows);
}

// Round 4
// 120.413 us; speedup vs baseline: 1.4206x; 1.4206x over previous
//
#include <hip/hip_runtime.h>
#include <hip/hip_bf16.h>

// Windowed attention smoothing via MFMA — barrier-free, per-wave autonomous.
// v5 = v3 (fp32 LDS band, proven ~42us) + three fixes:
//   1. amdgpu_waves_per_eu(4,4): stops the allocator's 64-VGPR/8-wave target
//      that spilled aw[]/stg[] in v1/v2/v4 (WRITE_SIZE +70MB signature).
//   2. M1 computed TRANSPOSED (accT = mfma(wfrag, am1) — same frags, swapped
//      roles), M2's B-frag gathered in-register via 16 ds_bpermute + select.
//      Kills the V1 LDS write->read round-trip on the critical chain and
//      frees 9216 B/block of LDS.
//   3. Band trimmed to 28 rows -> LDS 39680 B/block -> 4 blocks/CU ->
//      16 waves/CU (was 12). Grid 1024.
// No __syncthreads: LDS regions are wave-private; DS pipe is in-order
// within a wave. Band rows 28..31 (read by dead score rows) land in other
// waves' regions: values only feed Sc rows 26..31 which are never read.
//
// rows=200000, RANK=64, WINDOW=11. Block=256 (4 waves), 16 rows/wave/tile.

constexpr int RANK   = 64;
constexpr int WINDOW = 11;
constexpr int PAD    = 5;
constexpr int TILE   = 16;   // rows per wave
constexpr int BLOCK  = 256;  // 4 waves
constexpr int TR     = 64;   // rows per block-tile
constexpr int BROWS  = 28;   // staged band rows (rw-5 .. rw+22)
constexpr int BSTR   = 68;   // band row stride (floats): 272B, 16B-aligned,
                             // start bank advances 4/row -> frag reads ~2-way
constexpr int SC_S   = 18;   // f32 elems per Sc row (breaks pow2)
constexpr int GRIDB  = 1024; // 4 resident blocks/CU x 256 CU

constexpr int BAND_F = BROWS * BSTR;          // 1904 floats per wave
constexpr int SC_OFF = 4 * BAND_F;            // 7616 floats
constexpr int SMEMF  = SC_OFF + 4 * 32 * SC_S; // 9920 floats = 39680 B

typedef short short8  __attribute__((ext_vector_type(8)));
typedef float float4v __attribute__((ext_vector_type(4)));

__device__ __forceinline__ short8 cvt_bf8(float4 a, float4 b) {
    union { short8 s; __hip_bfloat162 h[4]; } u;
    u.h[0] = __float22bfloat162_rn(make_float2(a.x, a.y));
    u.h[1] = __float22bfloat162_rn(make_float2(a.z, a.w));
    u.h[2] = __float22bfloat162_rn(make_float2(b.x, b.y));
    u.h[3] = __float22bfloat162_rn(make_float2(b.z, b.w));
    return u.s;
}

__device__ __forceinline__ float fast_tanh(float x) {
    return 1.0f - 2.0f / (1.0f + __expf(2.0f * x));
}

__global__ __launch_bounds__(BLOCK)
__attribute__((amdgpu_waves_per_eu(4, 4)))
void attn_win_kernel(
    const float* __restrict__ A,   // (rows, 64)
    const float* __restrict__ W,   // (64, 64) row-major (out,in)
    const float* __restrict__ b,   // (64,)
    float* __restrict__ out,       // (rows, 64)
    int rows)
{
    // Flat LDS so the deliberate band-row over-reads (rows 28..31) stay
    // in-bounds of the block allocation.
    __shared__ __align__(16) float smem[SMEMF];

    const int lane = threadIdx.x & 63;
    const int wv   = threadIdx.x >> 6;
    const int m16  = lane & 15;
    const int quad = lane >> 4;
    const int sr   = lane >> 4;        // staging: row within group-of-4
    const int sc4  = (lane & 15) * 4;  // staging: col base (float4)

    float* const bandW = smem + wv * BAND_F;                 // [28][68]
    float* const ScW   = smem + SC_OFF + wv * 32 * SC_S;     // [32][18]

    // ---- Persistent W fragments (32 VGPRs) + per-lane bias, loaded ONCE ----
    short8 wfrag[4][2];  // [ct][kf]: W[ct*16+m16][kf*32 + quad*8 + j]
    #pragma unroll
    for (int ct = 0; ct < 4; ct++) {
        #pragma unroll
        for (int kf = 0; kf < 2; kf++) {
            const float4* p =
                (const float4*)(W + (ct * 16 + m16) * RANK + kf * 32 + quad * 8);
            wfrag[ct][kf] = cvt_bf8(p[0], p[1]);
        }
    }
    // Transposed-M1 bias: accT[ct] reg r holds neuron n = ct*16 + quad*4 + r
    float4 biasT[4];
    #pragma unroll
    for (int ct = 0; ct < 4; ct++)
        biasT[ct] = *(const float4*)(b + ct * 16 + quad * 4);

    // bpermute source-lane indices (byte units). Word w of B-frag comes from
    // lane m16 + 16*(2*(quad&1) + (w>>1)).
    const int idxA = 4 * m16 + 128 * (quad & 1);
    const int idxB = idxA + 64;

    const int n_btiles = (rows + TR - 1) / TR;
    int bt = blockIdx.x;
    if (bt >= n_btiles) return;

    // ---- prologue: stage FIRST tile's 28-row fp32 band (guarded) ----
    {
        const int rw0 = bt * TR + wv * TILE;
        #pragma unroll
        for (int ro = 0; ro < 7; ro++) {
            const int g = rw0 - PAD + ro * 4 + sr;
            float4 x = make_float4(0.f, 0.f, 0.f, 0.f);
            if ((unsigned)g < (unsigned)rows)
                x = *(const float4*)(A + (size_t)g * RANK + sc4);
            *(float4*)&bandW[(ro * 4 + sr) * BSTR + sc4] = x;
        }
    }

    for (; bt < n_btiles; bt += gridDim.x) {
        const int rw = bt * TR + wv * TILE;   // this wave's rows rw..rw+15

        // ---- am1 frags from band (fp32 -> bf16): A rows rw+m16 ----
        short8 am1[2];
        #pragma unroll
        for (int kf = 0; kf < 2; kf++) {
            const float4* pp =
                (const float4*)&bandW[(PAD + m16) * BSTR + kf * 32 + quad * 8];
            am1[kf] = cvt_bf8(pp[0], pp[1]);
        }

        // ---- M1 (transposed): accT[ct] = W-block(ct) x A^T + b ----
        // C element (row = quad*4+r within block ct, col = m16):
        //   v1T[n = ct*16+quad*4+r][m = m16]
        float4v accT[4];
        #pragma unroll
        for (int ct = 0; ct < 4; ct++)
            accT[ct] = (float4v){biasT[ct].x, biasT[ct].y,
                                 biasT[ct].z, biasT[ct].w};
        #pragma unroll
        for (int kf = 0; kf < 2; kf++)
            #pragma unroll
            for (int ct = 0; ct < 4; ct++)
                accT[ct] = __builtin_amdgcn_mfma_f32_16x16x32_bf16(
                    wfrag[ct][kf], am1[kf], accT[ct], 0, 0, 0);

        // ---- tanh + pack to bf16 pairs: pk[ct][u] = (v[2u], v[2u+1]) ----
        int pk[4][2];
        #pragma unroll
        for (int ct = 0; ct < 4; ct++)
            #pragma unroll
            for (int u = 0; u < 2; u++) {
                union { __hip_bfloat162 h; int i; } cv;
                cv.h = __float22bfloat162_rn(make_float2(
                    fast_tanh(accT[ct][2 * u]),
                    fast_tanh(accT[ct][2 * u + 1])));
                pk[ct][u] = cv.i;
            }

        // ---- M2 B-frag gather via ds_bpermute (no LDS storage) ----
        // Target lane (m16,quad), reg j needs v1[m16][quad*8+j+32kf]:
        //   source reg  pk[2kf + (quad>>1)][w&1]   (w = j>>1)
        //   source lane m16 + 16*(2*(quad&1) + (w>>1))
        short8 bfr[2];
        #pragma unroll
        for (int kf = 0; kf < 2; kf++) {
            union { int w[4]; short8 s; } u;
            #pragma unroll
            for (int w = 0; w < 4; w++) {
                const int idx = (w >> 1) ? idxB : idxA;
                const int lo = __builtin_amdgcn_ds_bpermute(idx, pk[2 * kf][w & 1]);
                const int hi = __builtin_amdgcn_ds_bpermute(idx, pk[2 * kf + 1][w & 1]);
                u.w[w] = (quad >= 2) ? hi : lo;
            }
            bfr[kf] = u.s;
        }

        // ---- abnd frags: band rows it*16+m16 (rows 28..31 are dead reads) ----
        short8 abnd[2][2];
        #pragma unroll
        for (int it = 0; it < 2; it++)
            #pragma unroll
            for (int kf = 0; kf < 2; kf++) {
                const float4* pp = (const float4*)
                    &bandW[(it * 16 + m16) * BSTR + kf * 32 + quad * 8];
                abnd[it][kf] = cvt_bf8(pp[0], pp[1]);
            }

        // ---- M2: S[i][q] = dot(band[i], v1[q]) ----
        float4v sacc[2];
        sacc[0] = (float4v){0.f, 0.f, 0.f, 0.f};
        sacc[1] = (float4v){0.f, 0.f, 0.f, 0.f};
        #pragma unroll
        for (int kf = 0; kf < 2; kf++)
            #pragma unroll
            for (int it = 0; it < 2; it++)
                sacc[it] = __builtin_amdgcn_mfma_f32_16x16x32_bf16(
                    abnd[it][kf], bfr[kf], sacc[it], 0, 0, 0);

        // scatter S (i = it*16+quad*4+rg, q = m16); rows >=26 are dead
        #pragma unroll
        for (int it = 0; it < 2; it++)
            #pragma unroll
            for (int rg = 0; rg < 4; rg++)
                ScW[(it * 16 + quad * 4 + rg) * SC_S + m16] = sacc[it][rg];

        // ---- issue NEXT tile's stage loads (latency hides under softmax/aw) ----
        float4 stg[7];
        {
            const int rwn = rw + (int)gridDim.x * TR;
            #pragma unroll
            for (int ro = 0; ro < 7; ro++) {
                const int g = rwn - PAD + ro * 4 + sr;
                stg[ro] = make_float4(0.f, 0.f, 0.f, 0.f);
                if ((unsigned)g < (unsigned)rows)
                    stg[ro] = *(const float4*)(A + (size_t)g * RANK + sc4);
            }
        }

        // ---- softmax over band i in [q, q+10] of column q=m16 ----
        // (redundant across quads; lane rr<16 holds row rw+rr's probs)
        float p[WINDOW];
        {
            float s[WINDOW];
            float mx = -1e30f;
            #pragma unroll
            for (int w = 0; w < WINDOW; w++) {
                s[w] = ScW[(m16 + w) * SC_S + m16];
                mx = fmaxf(mx, s[w]);
            }
            float den = 0.0f;
            #pragma unroll
            for (int w = 0; w < WINDOW; w++) {
                p[w] = __expf((s[w] - mx) * 0.125f);  // 1/sqrt(64) folded in
                den += p[w];
            }
            const float rden = __fdividef(1.0f, den);
            #pragma unroll
            for (int w = 0; w < WINDOW; w++) p[w] *= rden;
        }

        // ---- aw: fp32 window, last reads of the current band ----
        float aw[26];
        #pragma unroll
        for (int s = 0; s < 26; s++) aw[s] = bandW[s * BSTR + lane];

        // ---- overwrite band with NEXT tile's rows (DS in-order per wave) ----
        #pragma unroll
        for (int ro = 0; ro < 7; ro++)
            *(float4*)&bandW[(ro * 4 + sr) * BSTR + sc4] = stg[ro];

        // ---- P4: out[rw+rr][lane] = sum_w p[rr][w] * aw[rr+w] ----
        #pragma unroll
        for (int rr = 0; rr < TILE; rr++) {
            float o = 0.0f;
            #pragma unroll
            for (int w = 0; w < WINDOW; w++) {
                const float pw = __uint_as_float(
                    __builtin_amdgcn_readlane(__float_as_uint(p[w]), rr));
                o = fmaf(pw, aw[rr + w], o);
            }
            if (rw + rr < rows)   // wave-uniform scalar guard
                out[(size_t)(rw + rr) * RANK + lane] = o;
        }
    }
}

extern "C" void kernel_launch(void* const* d_in, const int* in_sizes, int n_in,
                              void* d_out, int out_size, void* d_ws, size_t ws_size,
                              hipStream_t stream) {
    const float* A = (const float*)d_in[0];
    const float* W = (const float*)d_in[1];
    const float* b = (const float*)d_in[2];
    float* out = (float*)d_out;

    const int rows     = in_sizes[0] / RANK;
    const int n_btiles = (rows + TR - 1) / TR;
    const int blocks   = n_btiles < GRIDB ? n_btiles : GRIDB;  // persistent

    hipLaunchKernelGGL(attn_win_kernel, dim3(blocks), dim3(BLOCK), 0, stream,
                       A, W, b, out, rows);
}